// Round 5
// baseline (1246.293 us; speedup 1.0000x reference)
//
#include <hip/hip_runtime.h>
#include <stdint.h>

// RPN GT matcher — exact JAX-semantics reimplementation.
// RNG (verified R3, passed): partitionable counter-mode, counter=(0, flat_idx),
// 32-bit draw = o0 ^ o1; split(key,n)[i] = both words of tf(key,(0,i)).
#define NANCH   262144      // anchors (== 2^18, required by key packing)
#define NB      4           // batch
#define NG      64          // gt boxes per image
#define TGT_FG  153         // int(0.3*512)
#define SB      512         // sample batch
#define IDXMASK 262143u     // 2^18-1, anchor-index field in sort keys

// ---- workspace layout (bytes); harness poisons ws with 0xAA each launch ----
#define WS_G2A      0                         // NB*NG f32 (atomicMax as u32)
#define WS_NUMPOS   1024                      // NB i32
#define WS_NEGCNT   1088                      // NB i32
#define WS_KTH      1152                      // NB u64
#define WS_TBG      1216                      // NB i32
#define WS_DOSAMP   1280                      // NB i32
#define WS_SAMPKEY  2048                      // NB*SB u64 (ends 18432)
#define WS_ZERO_WORDS 4608                    // zero [0,18432) as u32
#define WS_A2G      32768                     // NB*NANCH u8
#define WS_NEG      (WS_A2G + NB*NANCH)       // NB*NANCH u32
#define WS_POS      (WS_NEG + NB*NANCH*4)     // NB*NANCH u64  (~13.1 MB total)

struct RngKeys { uint32_t kp[NB][2]; uint32_t kn[NB][2]; };

// ---------------- threefry2x32-20, exactly as jax/_src/prng.py -------------
#define TFR(r) { x0 += x1; x1 = (x1 << (r)) | (x1 >> (32 - (r))); x1 ^= x0; }
__host__ __device__ inline void tf2x32(uint32_t k0, uint32_t k1,
                                       uint32_t x0, uint32_t x1,
                                       uint32_t &o0, uint32_t &o1) {
  uint32_t k2 = k0 ^ k1 ^ 0x1BD11BDAu;
  x0 += k0; x1 += k1;
  TFR(13) TFR(15) TFR(26) TFR(6)   x0 += k1; x1 += k2 + 1u;
  TFR(17) TFR(29) TFR(16) TFR(24)  x0 += k2; x1 += k0 + 2u;
  TFR(13) TFR(15) TFR(26) TFR(6)   x0 += k0; x1 += k1 + 3u;
  TFR(17) TFR(29) TFR(16) TFR(24)  x0 += k1; x1 += k2 + 4u;
  TFR(13) TFR(15) TFR(26) TFR(6)   x0 += k2; x1 += k0 + 5u;
  o0 = x0; o1 = x1;
}

// hash with per-element counter i: counter pair (0, i)
__host__ __device__ inline void tf_ctr(uint32_t k0, uint32_t k1, uint32_t i,
                                       uint32_t &o0, uint32_t &o1) {
  tf2x32(k0, k1, 0u, i, o0, o1);
}

// 32-bit random draw for flat element index: o0 ^ o1 (verified R3)
__device__ __forceinline__ uint32_t draw_bits(uint32_t k0, uint32_t k1,
                                              uint32_t idx) {
  uint32_t o0, o1;
  tf_ctr(k0, k1, idx, o0, o1);
  return o0 ^ o1;
}

// ---- fast threefry for the categorical hot loop: 1-op rotate guaranteed ----
#define ROTL1(x, r) __builtin_amdgcn_alignbit((x), (x), 32 - (r))
#define TFQ(r) { x0 += x1; x1 = ROTL1(x1, r); x1 ^= x0; }
// caller pre-applies +k0 to x0 and +k1 to x1 (x0 ctr word is 0 -> x0 = k0)
__device__ __forceinline__ uint32_t tf_bits_fast(uint32_t k0, uint32_t k1,
                                                 uint32_t k2, uint32_t x0,
                                                 uint32_t x1) {
  TFQ(13) TFQ(15) TFQ(26) TFQ(6)   x0 += k1; x1 += k2 + 1u;
  TFQ(17) TFQ(29) TFQ(16) TFQ(24)  x0 += k2; x1 += k0 + 2u;
  TFQ(13) TFQ(15) TFQ(26) TFQ(6)   x0 += k0; x1 += k1 + 3u;
  TFQ(17) TFQ(29) TFQ(16) TFQ(24)  x0 += k1; x1 += k2 + 4u;
  TFQ(13) TFQ(15) TFQ(26) TFQ(6)   x0 += k2; x1 += k0 + 5u;
  return x0 ^ x1;
}

// ------------- IoU, bit-identical across passes (no FP contraction) --------
__device__ __forceinline__ float box_area(float x1, float y1, float x2, float y2) {
#pragma clang fp contract(off)
  return ((x2 - x1) + 1.0f) * ((y2 - y1) + 1.0f);
}

__device__ __forceinline__ float iou_pair(float ax1, float ay1, float ax2, float ay2,
                                          float areaA, float gx1, float gy1,
                                          float gx2, float gy2, float areaB) {
#pragma clang fp contract(off)
  float ltx = fmaxf(ax1, gx1), lty = fmaxf(ay1, gy1);
  float rbx = fminf(ax2, gx2), rby = fminf(ay2, gy2);
  float w = fmaxf((rbx - ltx) + 1.0f, 0.0f);
  float h = fmaxf((rby - lty) + 1.0f, 0.0f);
  float inter = w * h;
  return inter / ((areaA + areaB) - inter);
}

// wave-aggregated list append (1 atomic per wave instead of per lane)
__device__ __forceinline__ int wave_push(int* counter) {
  unsigned long long mask = __ballot(1);
  int lane   = threadIdx.x & 63;
  int leader = __ffsll(mask) - 1;
  int prefix = __popcll(mask & ((1ull << lane) - 1ull));
  int total  = __popcll(mask);
  int base = 0;
  if (lane == leader) base = atomicAdd(counter, total);
  base = __shfl(base, leader, 64);
  return base + prefix;
}

// ---------------------------------------------------------------------------
__global__ __launch_bounds__(256) void k_init(unsigned int* w) {
  int i = blockIdx.x * 256 + threadIdx.x;
  if (i < WS_ZERO_WORDS) w[i] = 0u;
}

// Pass A: g2a_max[b][j] = max_a masked_iou. Lanes = gt index, serial anchors.
__global__ __launch_bounds__(256) void k_g2amax(
    const float4* __restrict__ boxes, const float4* __restrict__ gtb,
    const int* __restrict__ gti, const float* __restrict__ iminfo,
    unsigned int* __restrict__ g2a_u32) {
  int bx = blockIdx.x;
  int b = bx >> 8, chunk = bx & 255;          // NANCH/1024 = 256 chunks/batch
  int t = threadIdx.x, j = t & 63, sub = t >> 6;
  float4 g = gtb[b * NG + j];
  bool valid = (gti[b * NG + j] == 0);
  float areaB = box_area(g.x, g.y, g.z, g.w);
  float thrx = iminfo[b * 3 + 1] + 1.0f;      // im_w + STRADDLE + 1
  float thry = iminfo[b * 3 + 0] + 1.0f;      // im_h + STRADDLE + 1
  float m = 0.0f;
  int base = chunk * 1024 + sub * 256;
  #pragma unroll 2
  for (int i = 0; i < 256; ++i) {
    float4 bb = boxes[base + i];              // same addr across wave: broadcast
    bool inside = (bb.x >= -0.0f) && (bb.y >= -0.0f) && (bb.z < thrx) && (bb.w < thry);
    float areaA = box_area(bb.x, bb.y, bb.z, bb.w);
    float v = iou_pair(bb.x, bb.y, bb.z, bb.w, areaA, g.x, g.y, g.z, g.w, areaB);
    v = (inside && valid) ? v : 0.0f;
    m = fmaxf(m, v);
  }
  __shared__ float red[4][64];
  red[sub][j] = m;
  __syncthreads();
  if (t < 64) {
    float mm = fmaxf(fmaxf(red[0][t], red[1][t]), fmaxf(red[2][t], red[3][t]));
    atomicMax(&g2a_u32[b * NG + t], __float_as_uint(mm));  // iou>=0: u32 order==f32
  }
}

// Pass B: labels init, argmax gt, with_max, pos/neg compaction with RNG keys.
__global__ __launch_bounds__(256) void k_label(
    const float4* __restrict__ boxes, const float4* __restrict__ gtb,
    const int* __restrict__ gti, const float* __restrict__ iminfo,
    const float* __restrict__ g2a, float* __restrict__ labels,
    unsigned char* __restrict__ a2g, unsigned long long* __restrict__ pos_keys,
    unsigned int* __restrict__ neg_list, int* __restrict__ num_pos,
    int* __restrict__ neg_cnt, RngKeys rk) {
  int bx = blockIdx.x;
  int b = bx >> 10, blk = bx & 1023;          // NANCH/256 = 1024 blocks/batch
  int t = threadIdx.x;
  __shared__ float4 sg[NG];
  __shared__ float sab[NG], sval[NG], sadj[NG];
  if (t < NG) {
    float4 g = gtb[b * NG + t];
    sg[t] = g;
    sab[t] = box_area(g.x, g.y, g.z, g.w);
    sval[t] = (gti[b * NG + t] == 0) ? 1.0f : 0.0f;
    float gm = g2a[b * NG + t];
    sadj[t] = (gm == 0.0f) ? 1.0f : gm;       // avoid matching all-zero cols
  }
  __syncthreads();
  int a = blk * 256 + t;
  float4 bb = boxes[a];
  float thrx = iminfo[b * 3 + 1] + 1.0f, thry = iminfo[b * 3 + 0] + 1.0f;
  bool inside = (bb.x >= -0.0f) && (bb.y >= -0.0f) && (bb.z < thrx) && (bb.w < thry);
  float areaA = box_area(bb.x, bb.y, bb.z, bb.w);
  float maxv = 0.0f; int amax = 0; bool wm = false;
  #pragma unroll 8
  for (int j = 0; j < NG; ++j) {
    float4 g = sg[j];
    float v = iou_pair(bb.x, bb.y, bb.z, bb.w, areaA, g.x, g.y, g.z, g.w, sab[j]);
    v = (inside && (sval[j] != 0.0f)) ? v : 0.0f;
    wm = wm || (v == sadj[j]);                 // ensure_closest_box
    if (v > maxv) { maxv = v; amax = j; }      // first-max (== jnp.argmax)
  }
  bool pos = inside && (wm || (maxv >= 0.5f));
  bool neg = inside && (maxv < 0.3f);
  labels[b * NANCH + a] = pos ? 1.0f : -1.0f;
  a2g[b * NANCH + a] = (unsigned char)amax;
  if (pos) {
    // prio = uniform(kp,(n,)) -> monotone in bits>>9; key: prio desc, idx asc
    uint32_t bits = draw_bits(rk.kp[b][0], rk.kp[b][1], (uint32_t)a);
    unsigned long long key =
        (((unsigned long long)(bits >> 9)) << 18) | (unsigned long long)(IDXMASK - (uint32_t)a);
    int p = wave_push(&num_pos[b]);
    pos_keys[(size_t)b * NANCH + p] = key;
  }
  if (neg) {
    int q = wave_push(&neg_cnt[b]);
    neg_list[(size_t)b * NANCH + q] = (unsigned int)a;
  }
}

// 41-bit MSB radix-select: kth[b] = 153rd-largest pos key (0 if np<=153).
__global__ __launch_bounds__(256) void k_select(
    const unsigned long long* __restrict__ pos_keys, const int* __restrict__ num_pos,
    const int* __restrict__ neg_cnt, unsigned long long* __restrict__ kth,
    int* __restrict__ tbg, int* __restrict__ dosamp) {
  int b = blockIdx.x, t = threadIdx.x;
  __shared__ int cnt[256];
  int np = num_pos[b];
  int nf = np < TGT_FG ? np : TGT_FG;
  int targ = SB - nf;
  if (t == 0) { tbg[b] = targ; dosamp[b] = (neg_cnt[b] > targ) ? 1 : 0; }
  if (np <= TGT_FG) { if (t == 0) kth[b] = 0ull; return; }
  const unsigned long long* keys = pos_keys + (size_t)b * NANCH;
  unsigned long long pref = 0ull;
  int r = TGT_FG;
  for (int bit = 40; bit >= 0; --bit) {
    unsigned long long cand = pref | (1ull << bit);
    unsigned long long mask = ~((1ull << bit) - 1ull);
    int c = 0;
    for (int i = t; i < np; i += 256) c += ((keys[i] & mask) == cand) ? 1 : 0;
    cnt[t] = c; __syncthreads();
    for (int st = 128; st > 0; st >>= 1) { if (t < st) cnt[t] += cnt[t + st]; __syncthreads(); }
    int total = cnt[0]; __syncthreads();
    if (total >= r) pref = cand; else r -= total;
  }
  if (t == 0) kth[b] = pref;
}

// Disable positives below the top-153 priority threshold.
__global__ __launch_bounds__(256) void k_disable(
    const unsigned long long* __restrict__ pos_keys, const int* __restrict__ num_pos,
    const unsigned long long* __restrict__ kth, float* __restrict__ labels) {
  int b = blockIdx.x >> 6, blk = blockIdx.x & 63;
  int np = num_pos[b];
  if (np <= TGT_FG) return;
  unsigned long long K = kth[b];
  for (int i = blk * 256 + threadIdx.x; i < np; i += 64 * 256) {
    unsigned long long key = pos_keys[(size_t)b * NANCH + i];
    if (key < K) {
      int a = (int)(IDXMASK - (uint32_t)(key & (unsigned long long)IDXMASK));
      labels[b * NANCH + a] = -1.0f;
    }
  }
}

// categorical(kn, neg?0:-1e9, shape=(512,)) == per-draw key-argmax over negs.
// gumbel strictly monotone in bits>>9; exact-bit ties -> smallest flat index
// (encoded IDXMASK-a in key low bits).
// v3: (a) draws s >= tbg[b] are DISCARDED by the reference (valid_s mask) —
//     skip their blocks entirely (~30% of hashes when np>=153);
//     (b) manual named accumulators + straight-line 8 hashes per element to
//     defeat the R4 loop-interchange (VGPR=20 showed per-hash list reloads);
//     (c) 2-deep software-pipelined neg_list load.
#define CC  8    // chunks over the negative list
#define SPT 8    // draws per thread (SB/SPT = 64 draw groups)
__global__ __launch_bounds__(256) void k_cat(
    const unsigned int* __restrict__ neg_list, const int* __restrict__ neg_cnt,
    const int* __restrict__ tbg, unsigned long long* __restrict__ samp_key,
    RngKeys rk) {
  int bx = blockIdx.x;
  int c = bx & (CC - 1);                 // chunk
  int g = (bx >> 3) & 63;                // draw group (SB/SPT = 64)
  int b = bx >> 9;                       // batch
  int targ = tbg[b];
  int s0 = g * SPT;
  if (s0 >= targ) return;                // dead draws: reference discards them
  int nn = neg_cnt[b];
  uint32_t k0 = rk.kn[b][0], k1 = rk.kn[b][1];
  uint32_t k2 = k0 ^ k1 ^ 0x1BD11BDAu;
  const uint32_t xb0 = ((uint32_t)(s0 + 0) << 18) + k1;
  const uint32_t xb1 = ((uint32_t)(s0 + 1) << 18) + k1;
  const uint32_t xb2 = ((uint32_t)(s0 + 2) << 18) + k1;
  const uint32_t xb3 = ((uint32_t)(s0 + 3) << 18) + k1;
  const uint32_t xb4 = ((uint32_t)(s0 + 4) << 18) + k1;
  const uint32_t xb5 = ((uint32_t)(s0 + 5) << 18) + k1;
  const uint32_t xb6 = ((uint32_t)(s0 + 6) << 18) + k1;
  const uint32_t xb7 = ((uint32_t)(s0 + 7) << 18) + k1;
  unsigned long long b0 = 0, b1 = 0, b2 = 0, b3 = 0,
                     b4 = 0, b5 = 0, b6 = 0, b7 = 0;
  const unsigned int* nl = neg_list + (size_t)b * NANCH;
  const int step = CC * 256;
  int i = c * 256 + (int)threadIdx.x;
  if (i < nn) {
    uint32_t a = nl[i];
    for (;;) {
      int inext = i + step;
      bool has = inext < nn;
      uint32_t a_next = has ? nl[inext] : 0u;
      unsigned long long inv64 = (unsigned long long)(IDXMASK - a);
#define HASH1(J) { \
      uint32_t bits = tf_bits_fast(k0, k1, k2, k0, xb##J + a); \
      unsigned long long key = \
          (((unsigned long long)(bits >> 9)) << 18) | inv64; \
      if (key > b##J) b##J = key; }
      HASH1(0) HASH1(1) HASH1(2) HASH1(3) HASH1(4) HASH1(5) HASH1(6) HASH1(7)
#undef HASH1
      if (!has) break;
      a = a_next; i = inext;
    }
  }
  // wave butterfly reduction (64 lanes), then cross-wave merge in LDS
  unsigned long long best[SPT] = {b0, b1, b2, b3, b4, b5, b6, b7};
  #pragma unroll
  for (int j = 0; j < SPT; ++j) {
    #pragma unroll
    for (int off = 32; off > 0; off >>= 1) {
      unsigned long long o = __shfl_xor(best[j], off, 64);
      if (o > best[j]) best[j] = o;
    }
  }
  __shared__ unsigned long long wred[4][SPT];
  int lane = threadIdx.x & 63, wid = threadIdx.x >> 6;
  if (lane == 0) {
    #pragma unroll
    for (int j = 0; j < SPT; ++j) wred[wid][j] = best[j];
  }
  __syncthreads();
  if (threadIdx.x < SPT && s0 + (int)threadIdx.x < targ) {
    int j = threadIdx.x;
    unsigned long long m = wred[0][j];
    if (wred[1][j] > m) m = wred[1][j];
    if (wred[2][j] > m) m = wred[2][j];
    if (wred[3][j] > m) m = wred[3][j];
    atomicMax(&samp_key[b * SB + s0 + j], m);
  }
}

// Set sampled negatives to 0 (after fg-disable, matching reference order).
__global__ __launch_bounds__(256) void k_scatter(
    const unsigned long long* __restrict__ samp_key, const int* __restrict__ tbg,
    const int* __restrict__ dosamp, float* __restrict__ labels) {
  int b = blockIdx.x >> 1;
  int s = ((blockIdx.x & 1) << 8) | threadIdx.x;
  if (!dosamp[b]) return;
  if (s < tbg[b]) {
    unsigned long long key = samp_key[b * SB + s];
    int a = (int)(IDXMASK - (uint32_t)(key & (unsigned long long)IDXMASK));
    labels[b * NANCH + a] = 0.0f;
  }
}

// bbox_transform_inv for final positives; zeros elsewhere.
__global__ __launch_bounds__(256) void k_targets(
    const float4* __restrict__ boxes, const float4* __restrict__ gtb,
    const unsigned char* __restrict__ a2g, const float* __restrict__ labels,
    float4* __restrict__ tout) {
  int bx = blockIdx.x;
  int b = bx >> 10, blk = bx & 1023;
  int a = blk * 256 + threadIdx.x;
  float lab = labels[b * NANCH + a];
  float4 o = make_float4(0.f, 0.f, 0.f, 0.f);
  if (lab > 0.0f) {
    float4 e = boxes[a];
    float4 g = gtb[b * NG + a2g[b * NANCH + a]];
    float ew = e.z - e.x + 1.0f, eh = e.w - e.y + 1.0f;
    float ecx = e.x + 0.5f * ew, ecy = e.y + 0.5f * eh;
    float gw = g.z - g.x + 1.0f, gh = g.w - g.y + 1.0f;
    float gcx = g.x + 0.5f * gw, gcy = g.y + 0.5f * gh;
    o.x = (gcx - ecx) / ew;
    o.y = (gcy - ecy) / eh;
    o.z = logf(gw / ew);
    o.w = logf(gh / eh);
  }
  tout[(size_t)b * NANCH + a] = o;
}

// ---------------------------------------------------------------------------
extern "C" void kernel_launch(void* const* d_in, const int* in_sizes, int n_in,
                              void* d_out, int out_size, void* d_ws, size_t ws_size,
                              hipStream_t stream) {
  const float4* boxes  = (const float4*)d_in[0];
  const float4* gtb    = (const float4*)d_in[1];
  // d_in[2] = gt_labels: unused, exactly like the reference
  const int*    gti    = (const int*)d_in[3];
  const float*  iminfo = (const float*)d_in[4];
  float*  labels = (float*)d_out;                       // [B][N] as f32
  float4* tout   = (float4*)(labels + (size_t)NB * NANCH); // [B][N][4]

  char* wsb = (char*)d_ws;  // needs ~13.1 MB
  unsigned int*       g2a_u32  = (unsigned int*)(wsb + WS_G2A);
  float*              g2a_f    = (float*)(wsb + WS_G2A);
  int*                num_pos  = (int*)(wsb + WS_NUMPOS);
  int*                neg_cnt  = (int*)(wsb + WS_NEGCNT);
  unsigned long long* kth      = (unsigned long long*)(wsb + WS_KTH);
  int*                tbg      = (int*)(wsb + WS_TBG);
  int*                dosamp   = (int*)(wsb + WS_DOSAMP);
  unsigned long long* samp_key = (unsigned long long*)(wsb + WS_SAMPKEY);
  unsigned char*      a2g      = (unsigned char*)(wsb + WS_A2G);
  unsigned int*       neg_list = (unsigned int*)(wsb + WS_NEG);
  unsigned long long* pos_keys = (unsigned long long*)(wsb + WS_POS);

  // Host-side key derivation: root=(0,42); split(root,4) -> per-image key;
  // split(key_b,2) -> (kp, kn). Split keys are the FULL 64-bit outputs
  // (no XOR — _threefry_split_foldlike stacks both words).
  RngKeys rk;
  for (int b = 0; b < NB; ++b) {
    uint32_t a0, a1;
    tf_ctr(0u, 42u, (uint32_t)b, a0, a1);                // keys[b]
    tf_ctr(a0, a1, 0u, rk.kp[b][0], rk.kp[b][1]);        // subkey 0 = kp
    tf_ctr(a0, a1, 1u, rk.kn[b][0], rk.kn[b][1]);        // subkey 1 = kn
  }

  k_init   <<<18, 256, 0, stream>>>((unsigned int*)wsb);
  k_g2amax <<<NB * (NANCH / 1024), 256, 0, stream>>>(boxes, gtb, gti, iminfo, g2a_u32);
  k_label  <<<NB * (NANCH / 256), 256, 0, stream>>>(boxes, gtb, gti, iminfo, g2a_f,
                                                    labels, a2g, pos_keys, neg_list,
                                                    num_pos, neg_cnt, rk);
  k_select <<<NB, 256, 0, stream>>>(pos_keys, num_pos, neg_cnt, kth, tbg, dosamp);
  k_disable<<<NB * 64, 256, 0, stream>>>(pos_keys, num_pos, kth, labels);
  k_cat    <<<NB * (SB / SPT) * CC, 256, 0, stream>>>(neg_list, neg_cnt, tbg,
                                                      samp_key, rk);
  k_scatter<<<NB * 2, 256, 0, stream>>>(samp_key, tbg, dosamp, labels);
  k_targets<<<NB * (NANCH / 256), 256, 0, stream>>>(boxes, gtb, a2g, labels, tout);
}

// Round 6
// 891.612 us; speedup vs baseline: 1.3978x; 1.3978x over previous
//
#include <hip/hip_runtime.h>
#include <stdint.h>

// RPN GT matcher — exact JAX-semantics reimplementation.
// RNG (verified R3): partitionable counter-mode, counter=(0, flat_idx),
// 32-bit draw = o0 ^ o1; split(key,n)[i] = both words of tf(key,(0,i)).
#define NANCH   262144      // anchors (== 2^18, required by key packing)
#define NB      4           // batch
#define NG      64          // gt boxes per image
#define TGT_FG  153         // int(0.3*512)
#define SB      512         // sample batch
#define IDXMASK 262143u     // 2^18-1, anchor-index field in sort keys
#define NSH     8           // shards per batch (atomic-contention spreading)
#define SHCAP   (NANCH/NSH) // 32768 = 128 blocks * 256 anchors (exact fit)

// ---- workspace layout (bytes); harness poisons ws with 0xAA each launch ----
// padded counters: one counter per 64-B line: idx = (b*NSH+sh)*2 + (0=pos,1=neg)
#define WS_PCNT     0                         // 64 lines * 64 B = 4096
#define WS_G2A      4096                      // NB*NG f32 = 1024
#define WS_KTH      5120                      // NB u64
#define WS_TBG      5184                      // NB i32
#define WS_DOSAMP   5248                      // NB i32
#define WS_NUMPOS   5312                      // NB i32
#define WS_SAMPKEY  8192                      // NB*SB u64 -> ends 24576
#define WS_ZERO_WORDS 6144                    // zero [0, 24576) as u32
#define WS_A2G      32768                     // NB*NANCH u8
#define WS_NEG      (WS_A2G + NB*NANCH)       // NB*NANCH u32 (8 shards/batch)
#define WS_POS      (WS_NEG + NB*NANCH*4)     // NB*NANCH u64 (8 shards/batch)

#define PCNT_AT(pcnt, b, sh, L) ((pcnt)[(((b) * NSH + (sh)) * 2 + (L)) * 16])

struct RngKeys { uint32_t kp[NB][2]; uint32_t kn[NB][2]; };

// ---------------- threefry2x32-20, exactly as jax/_src/prng.py -------------
#define TFR(r) { x0 += x1; x1 = (x1 << (r)) | (x1 >> (32 - (r))); x1 ^= x0; }
__host__ __device__ inline void tf2x32(uint32_t k0, uint32_t k1,
                                       uint32_t x0, uint32_t x1,
                                       uint32_t &o0, uint32_t &o1) {
  uint32_t k2 = k0 ^ k1 ^ 0x1BD11BDAu;
  x0 += k0; x1 += k1;
  TFR(13) TFR(15) TFR(26) TFR(6)   x0 += k1; x1 += k2 + 1u;
  TFR(17) TFR(29) TFR(16) TFR(24)  x0 += k2; x1 += k0 + 2u;
  TFR(13) TFR(15) TFR(26) TFR(6)   x0 += k0; x1 += k1 + 3u;
  TFR(17) TFR(29) TFR(16) TFR(24)  x0 += k1; x1 += k2 + 4u;
  TFR(13) TFR(15) TFR(26) TFR(6)   x0 += k2; x1 += k0 + 5u;
  o0 = x0; o1 = x1;
}

// hash with per-element counter i: counter pair (0, i)
__host__ __device__ inline void tf_ctr(uint32_t k0, uint32_t k1, uint32_t i,
                                       uint32_t &o0, uint32_t &o1) {
  tf2x32(k0, k1, 0u, i, o0, o1);
}

// 32-bit random draw for flat element index: o0 ^ o1 (verified R3)
__device__ __forceinline__ uint32_t draw_bits(uint32_t k0, uint32_t k1,
                                              uint32_t idx) {
  uint32_t o0, o1;
  tf_ctr(k0, k1, idx, o0, o1);
  return o0 ^ o1;
}

// ---- threefry core for the categorical hot loop (rotate = alignbit) -------
#define ROTL1(x, r) __builtin_amdgcn_alignbit((x), (x), 32 - (r))
#define TFQ(r) { x0 += x1; x1 = ROTL1(x1, r); x1 ^= x0; }
// caller pre-applies +k0 to x0 and +k1 to x1 (x0 ctr word is 0 -> x0 = k0)
__device__ __forceinline__ uint32_t tf_bits_fast(uint32_t k0, uint32_t k1,
                                                 uint32_t k2, uint32_t x0,
                                                 uint32_t x1) {
  TFQ(13) TFQ(15) TFQ(26) TFQ(6)   x0 += k1; x1 += k2 + 1u;
  TFQ(17) TFQ(29) TFQ(16) TFQ(24)  x0 += k2; x1 += k0 + 2u;
  TFQ(13) TFQ(15) TFQ(26) TFQ(6)   x0 += k0; x1 += k1 + 3u;
  TFQ(17) TFQ(29) TFQ(16) TFQ(24)  x0 += k1; x1 += k2 + 4u;
  TFQ(13) TFQ(15) TFQ(26) TFQ(6)   x0 += k2; x1 += k0 + 5u;
  return x0 ^ x1;
}

// ------------- IoU, bit-identical across passes (no FP contraction) --------
__device__ __forceinline__ float box_area(float x1, float y1, float x2, float y2) {
#pragma clang fp contract(off)
  return ((x2 - x1) + 1.0f) * ((y2 - y1) + 1.0f);
}

__device__ __forceinline__ float iou_pair(float ax1, float ay1, float ax2, float ay2,
                                          float areaA, float gx1, float gy1,
                                          float gx2, float gy2, float areaB) {
#pragma clang fp contract(off)
  float ltx = fmaxf(ax1, gx1), lty = fmaxf(ay1, gy1);
  float rbx = fminf(ax2, gx2), rby = fminf(ay2, gy2);
  float w = fmaxf((rbx - ltx) + 1.0f, 0.0f);
  float h = fmaxf((rby - lty) + 1.0f, 0.0f);
  float inter = w * h;
  return inter / ((areaA + areaB) - inter);
}

// ---------------------------------------------------------------------------
__global__ __launch_bounds__(256) void k_init(unsigned int* w) {
  int i = blockIdx.x * 256 + threadIdx.x;
  if (i < WS_ZERO_WORDS) w[i] = 0u;
}

// Pass A: g2a_max[b][j] = max_a masked_iou. Lanes = gt index, serial anchors.
__global__ __launch_bounds__(256) void k_g2amax(
    const float4* __restrict__ boxes, const float4* __restrict__ gtb,
    const int* __restrict__ gti, const float* __restrict__ iminfo,
    unsigned int* __restrict__ g2a_u32) {
  int bx = blockIdx.x;
  int b = bx >> 8, chunk = bx & 255;          // NANCH/1024 = 256 chunks/batch
  int t = threadIdx.x, j = t & 63, sub = t >> 6;
  float4 g = gtb[b * NG + j];
  bool valid = (gti[b * NG + j] == 0);
  float areaB = box_area(g.x, g.y, g.z, g.w);
  float thrx = iminfo[b * 3 + 1] + 1.0f;      // im_w + STRADDLE + 1
  float thry = iminfo[b * 3 + 0] + 1.0f;      // im_h + STRADDLE + 1
  float m = 0.0f;
  int base = chunk * 1024 + sub * 256;
  #pragma unroll 2
  for (int i = 0; i < 256; ++i) {
    float4 bb = boxes[base + i];              // same addr across wave: broadcast
    bool inside = (bb.x >= -0.0f) && (bb.y >= -0.0f) && (bb.z < thrx) && (bb.w < thry);
    float areaA = box_area(bb.x, bb.y, bb.z, bb.w);
    float v = iou_pair(bb.x, bb.y, bb.z, bb.w, areaA, g.x, g.y, g.z, g.w, areaB);
    v = (inside && valid) ? v : 0.0f;
    m = fmaxf(m, v);
  }
  __shared__ float red[4][64];
  red[sub][j] = m;
  __syncthreads();
  if (t < 64) {
    float mm = fmaxf(fmaxf(red[0][t], red[1][t]), fmaxf(red[2][t], red[3][t]));
    atomicMax(&g2a_u32[b * NG + t], __float_as_uint(mm));  // iou>=0: u32 order==f32
  }
}

// Pass B: labels init, argmax gt, with_max, pos/neg compaction (sharded,
// block-aggregated atomics: 1 atomic per block per list, padded counters).
__global__ __launch_bounds__(256) void k_label(
    const float4* __restrict__ boxes, const float4* __restrict__ gtb,
    const int* __restrict__ gti, const float* __restrict__ iminfo,
    const float* __restrict__ g2a, float* __restrict__ labels,
    unsigned char* __restrict__ a2g, unsigned long long* __restrict__ pos_keys,
    unsigned int* __restrict__ neg_list, int* __restrict__ pcnt, RngKeys rk) {
  int bx = blockIdx.x;
  int b = bx >> 10, blk = bx & 1023;          // NANCH/256 = 1024 blocks/batch
  int t = threadIdx.x;
  int sh = blk & (NSH - 1);                   // 128 blocks/shard * 256 = SHCAP
  __shared__ float4 sg[NG];
  __shared__ float sab[NG], sval[NG], sadj[NG];
  if (t < NG) {
    float4 g = gtb[b * NG + t];
    sg[t] = g;
    sab[t] = box_area(g.x, g.y, g.z, g.w);
    sval[t] = (gti[b * NG + t] == 0) ? 1.0f : 0.0f;
    float gm = g2a[b * NG + t];
    sadj[t] = (gm == 0.0f) ? 1.0f : gm;       // avoid matching all-zero cols
  }
  __syncthreads();
  int a = blk * 256 + t;
  float4 bb = boxes[a];
  float thrx = iminfo[b * 3 + 1] + 1.0f, thry = iminfo[b * 3 + 0] + 1.0f;
  bool inside = (bb.x >= -0.0f) && (bb.y >= -0.0f) && (bb.z < thrx) && (bb.w < thry);
  float areaA = box_area(bb.x, bb.y, bb.z, bb.w);
  float maxv = 0.0f; int amax = 0; bool wm = false;
  #pragma unroll 8
  for (int j = 0; j < NG; ++j) {
    float4 g = sg[j];
    float v = iou_pair(bb.x, bb.y, bb.z, bb.w, areaA, g.x, g.y, g.z, g.w, sab[j]);
    v = (inside && (sval[j] != 0.0f)) ? v : 0.0f;
    wm = wm || (v == sadj[j]);                 // ensure_closest_box
    if (v > maxv) { maxv = v; amax = j; }      // first-max (== jnp.argmax)
  }
  bool pos = inside && (wm || (maxv >= 0.5f));
  bool neg = inside && (maxv < 0.3f);
  labels[b * NANCH + a] = pos ? 1.0f : -1.0f;
  a2g[b * NANCH + a] = (unsigned char)amax;
  // block-aggregated two-list compaction
  unsigned long long mpos = __ballot(pos);
  unsigned long long mneg = __ballot(neg);
  int lane = t & 63, wid = t >> 6;
  __shared__ int wc[4][2];
  __shared__ int bbase[2];
  if (lane == 0) { wc[wid][0] = __popcll(mpos); wc[wid][1] = __popcll(mneg); }
  __syncthreads();
  if (t == 0) {
    bbase[0] = atomicAdd(&PCNT_AT(pcnt, b, sh, 0),
                         wc[0][0] + wc[1][0] + wc[2][0] + wc[3][0]);
    bbase[1] = atomicAdd(&PCNT_AT(pcnt, b, sh, 1),
                         wc[0][1] + wc[1][1] + wc[2][1] + wc[3][1]);
  }
  __syncthreads();
  unsigned long long lt = (1ull << lane) - 1ull;
  if (pos) {
    int off = bbase[0] + __popcll(mpos & lt);
    for (int w = 0; w < wid; ++w) off += wc[w][0];
    // prio = uniform(kp,(n,)) -> monotone in bits>>9; key: prio desc, idx asc
    uint32_t bits = draw_bits(rk.kp[b][0], rk.kp[b][1], (uint32_t)a);
    unsigned long long key =
        (((unsigned long long)(bits >> 9)) << 18) | (unsigned long long)(IDXMASK - (uint32_t)a);
    pos_keys[(size_t)b * NANCH + (size_t)sh * SHCAP + off] = key;
  }
  if (neg) {
    int off = bbase[1] + __popcll(mneg & lt);
    for (int w = 0; w < wid; ++w) off += wc[w][1];
    neg_list[(size_t)b * NANCH + (size_t)sh * SHCAP + off] = (unsigned int)a;
  }
}

// 41-bit MSB radix-select: kth[b] = 153rd-largest pos key (0 if np<=153).
__global__ __launch_bounds__(256) void k_select(
    const unsigned long long* __restrict__ pos_keys, const int* __restrict__ pcnt,
    unsigned long long* __restrict__ kth, int* __restrict__ tbg,
    int* __restrict__ dosamp, int* __restrict__ numpos) {
  int b = blockIdx.x, t = threadIdx.x;
  int scnt[NSH]; int np = 0, nn = 0;
  #pragma unroll
  for (int sh = 0; sh < NSH; ++sh) {
    scnt[sh] = PCNT_AT(pcnt, b, sh, 0);
    np += scnt[sh];
    nn += PCNT_AT(pcnt, b, sh, 1);
  }
  int nf = np < TGT_FG ? np : TGT_FG;
  int targ = SB - nf;
  if (t == 0) { tbg[b] = targ; dosamp[b] = (nn > targ) ? 1 : 0; numpos[b] = np; }
  if (np <= TGT_FG) { if (t == 0) kth[b] = 0ull; return; }
  __shared__ int cw[4];
  int lane = t & 63, wid = t >> 6;
  unsigned long long pref = 0ull;
  int r = TGT_FG;
  for (int bit = 40; bit >= 0; --bit) {
    unsigned long long cand = pref | (1ull << bit);
    unsigned long long mask = ~((1ull << bit) - 1ull);
    int c = 0;
    for (int sh = 0; sh < NSH; ++sh) {
      const unsigned long long* keys =
          pos_keys + (size_t)b * NANCH + (size_t)sh * SHCAP;
      for (int i = t; i < scnt[sh]; i += 256)
        c += ((keys[i] & mask) == cand) ? 1 : 0;
    }
    #pragma unroll
    for (int off = 32; off; off >>= 1) c += __shfl_xor(c, off, 64);
    __syncthreads();
    if (lane == 0) cw[wid] = c;
    __syncthreads();
    int total = cw[0] + cw[1] + cw[2] + cw[3];
    if (total >= r) pref = cand; else r -= total;
  }
  if (t == 0) kth[b] = pref;
}

// Disable positives below the top-153 priority threshold.
__global__ __launch_bounds__(256) void k_disable(
    const unsigned long long* __restrict__ pos_keys, const int* __restrict__ pcnt,
    const int* __restrict__ numpos, const unsigned long long* __restrict__ kth,
    float* __restrict__ labels) {
  int b = blockIdx.x >> 6, blk = blockIdx.x & 63;
  if (numpos[b] <= TGT_FG) return;
  int sh = blk & (NSH - 1), sub = blk >> 3;
  int cnt = PCNT_AT(pcnt, b, sh, 0);
  unsigned long long K = kth[b];
  const unsigned long long* keys = pos_keys + (size_t)b * NANCH + (size_t)sh * SHCAP;
  for (int i = sub * 256 + threadIdx.x; i < cnt; i += 8 * 256) {
    unsigned long long key = keys[i];
    if (key < K) {
      int a = (int)(IDXMASK - (uint32_t)(key & (unsigned long long)IDXMASK));
      labels[b * NANCH + a] = -1.0f;
    }
  }
}

// categorical(kn, neg?0:-1e9, shape=(512,)) == per-draw key-argmax over negs.
// gumbel strictly monotone in bits>>9; exact-bit ties -> smallest flat index.
// v4: R3's proven high-busy structure + tbg-skip + 2 draws/block (named u64
// accumulators, small enough to stay in registers) + shard as grid dim.
__global__ __launch_bounds__(256) void k_cat(
    const unsigned int* __restrict__ neg_list, const int* __restrict__ pcnt,
    const int* __restrict__ tbg, unsigned long long* __restrict__ samp_key,
    RngKeys rk) {
  int bx = blockIdx.x;
  int sh = bx & (NSH - 1);               // shard = chunk of the negative list
  int pr = (bx >> 3) & 255;              // draw pair (s0 = 2*pr)
  int b  = bx >> 11;                     // batch
  int targ = tbg[b];
  int s0 = pr * 2;
  if (s0 >= targ) return;                // dead draws: reference discards them
  int nn = PCNT_AT(pcnt, b, sh, 1);
  uint32_t k0 = rk.kn[b][0], k1 = rk.kn[b][1];
  uint32_t k2 = k0 ^ k1 ^ 0x1BD11BDAu;
  uint32_t xb0 = ((uint32_t)s0 << 18) + k1;
  uint32_t xb1 = ((uint32_t)(s0 + 1) << 18) + k1;
  unsigned long long b0 = 0ull, b1 = 0ull;
  const unsigned int* nl = neg_list + (size_t)b * NANCH + (size_t)sh * SHCAP;
  int i = threadIdx.x;
  if (i < nn) {
    uint32_t a = nl[i];
    for (;;) {
      int inext = i + 256;
      bool has = inext < nn;
      uint32_t an = has ? nl[inext] : 0u;    // 1-deep pipelined load
      unsigned long long inv64 = (unsigned long long)(IDXMASK - a);
      { uint32_t bits = tf_bits_fast(k0, k1, k2, k0, xb0 + a);
        unsigned long long key = (((unsigned long long)(bits >> 9)) << 18) | inv64;
        if (key > b0) b0 = key; }
      { uint32_t bits = tf_bits_fast(k0, k1, k2, k0, xb1 + a);
        unsigned long long key = (((unsigned long long)(bits >> 9)) << 18) | inv64;
        if (key > b1) b1 = key; }
      if (!has) break;
      a = an; i = inext;
    }
  }
  // wave butterfly, then cross-wave merge
  #pragma unroll
  for (int off = 32; off; off >>= 1) {
    unsigned long long o0 = __shfl_xor(b0, off, 64); if (o0 > b0) b0 = o0;
    unsigned long long o1 = __shfl_xor(b1, off, 64); if (o1 > b1) b1 = o1;
  }
  __shared__ unsigned long long red[4][2];
  int lane = threadIdx.x & 63, wid = threadIdx.x >> 6;
  if (lane == 0) { red[wid][0] = b0; red[wid][1] = b1; }
  __syncthreads();
  if (threadIdx.x < 2) {
    int j = threadIdx.x;
    unsigned long long m = red[0][j];
    if (red[1][j] > m) m = red[1][j];
    if (red[2][j] > m) m = red[2][j];
    if (red[3][j] > m) m = red[3][j];
    if (s0 + j < targ) atomicMax(&samp_key[b * SB + s0 + j], m);
  }
}

// Set sampled negatives to 0 (after fg-disable, matching reference order).
__global__ __launch_bounds__(256) void k_scatter(
    const unsigned long long* __restrict__ samp_key, const int* __restrict__ tbg,
    const int* __restrict__ dosamp, float* __restrict__ labels) {
  int b = blockIdx.x >> 1;
  int s = ((blockIdx.x & 1) << 8) | threadIdx.x;
  if (!dosamp[b]) return;
  if (s < tbg[b]) {
    unsigned long long key = samp_key[b * SB + s];
    int a = (int)(IDXMASK - (uint32_t)(key & (unsigned long long)IDXMASK));
    labels[b * NANCH + a] = 0.0f;
  }
}

// bbox_transform_inv for final positives; zeros elsewhere.
__global__ __launch_bounds__(256) void k_targets(
    const float4* __restrict__ boxes, const float4* __restrict__ gtb,
    const unsigned char* __restrict__ a2g, const float* __restrict__ labels,
    float4* __restrict__ tout) {
  int bx = blockIdx.x;
  int b = bx >> 10, blk = bx & 1023;
  int a = blk * 256 + threadIdx.x;
  float lab = labels[b * NANCH + a];
  float4 o = make_float4(0.f, 0.f, 0.f, 0.f);
  if (lab > 0.0f) {
    float4 e = boxes[a];
    float4 g = gtb[b * NG + a2g[b * NANCH + a]];
    float ew = e.z - e.x + 1.0f, eh = e.w - e.y + 1.0f;
    float ecx = e.x + 0.5f * ew, ecy = e.y + 0.5f * eh;
    float gw = g.z - g.x + 1.0f, gh = g.w - g.y + 1.0f;
    float gcx = g.x + 0.5f * gw, gcy = g.y + 0.5f * gh;
    o.x = (gcx - ecx) / ew;
    o.y = (gcy - ecy) / eh;
    o.z = logf(gw / ew);
    o.w = logf(gh / eh);
  }
  tout[(size_t)b * NANCH + a] = o;
}

// ---------------------------------------------------------------------------
extern "C" void kernel_launch(void* const* d_in, const int* in_sizes, int n_in,
                              void* d_out, int out_size, void* d_ws, size_t ws_size,
                              hipStream_t stream) {
  const float4* boxes  = (const float4*)d_in[0];
  const float4* gtb    = (const float4*)d_in[1];
  // d_in[2] = gt_labels: unused, exactly like the reference
  const int*    gti    = (const int*)d_in[3];
  const float*  iminfo = (const float*)d_in[4];
  float*  labels = (float*)d_out;                       // [B][N] as f32
  float4* tout   = (float4*)(labels + (size_t)NB * NANCH); // [B][N][4]

  char* wsb = (char*)d_ws;  // needs ~13.1 MB
  int*                pcnt     = (int*)(wsb + WS_PCNT);
  unsigned int*       g2a_u32  = (unsigned int*)(wsb + WS_G2A);
  float*              g2a_f    = (float*)(wsb + WS_G2A);
  unsigned long long* kth      = (unsigned long long*)(wsb + WS_KTH);
  int*                tbg      = (int*)(wsb + WS_TBG);
  int*                dosamp   = (int*)(wsb + WS_DOSAMP);
  int*                numpos   = (int*)(wsb + WS_NUMPOS);
  unsigned long long* samp_key = (unsigned long long*)(wsb + WS_SAMPKEY);
  unsigned char*      a2g      = (unsigned char*)(wsb + WS_A2G);
  unsigned int*       neg_list = (unsigned int*)(wsb + WS_NEG);
  unsigned long long* pos_keys = (unsigned long long*)(wsb + WS_POS);

  // Host-side key derivation: root=(0,42); split(root,4) -> per-image key;
  // split(key_b,2) -> (kp, kn). Split keys are the FULL 64-bit outputs.
  RngKeys rk;
  for (int b = 0; b < NB; ++b) {
    uint32_t a0, a1;
    tf_ctr(0u, 42u, (uint32_t)b, a0, a1);                // keys[b]
    tf_ctr(a0, a1, 0u, rk.kp[b][0], rk.kp[b][1]);        // subkey 0 = kp
    tf_ctr(a0, a1, 1u, rk.kn[b][0], rk.kn[b][1]);        // subkey 1 = kn
  }

  k_init   <<<24, 256, 0, stream>>>((unsigned int*)wsb);
  k_g2amax <<<NB * (NANCH / 1024), 256, 0, stream>>>(boxes, gtb, gti, iminfo, g2a_u32);
  k_label  <<<NB * (NANCH / 256), 256, 0, stream>>>(boxes, gtb, gti, iminfo, g2a_f,
                                                    labels, a2g, pos_keys, neg_list,
                                                    pcnt, rk);
  k_select <<<NB, 256, 0, stream>>>(pos_keys, pcnt, kth, tbg, dosamp, numpos);
  k_disable<<<NB * 64, 256, 0, stream>>>(pos_keys, pcnt, numpos, kth, labels);
  k_cat    <<<NB * 256 * NSH, 256, 0, stream>>>(neg_list, pcnt, tbg, samp_key, rk);
  k_scatter<<<NB * 2, 256, 0, stream>>>(samp_key, tbg, dosamp, labels);
  k_targets<<<NB * (NANCH / 256), 256, 0, stream>>>(boxes, gtb, a2g, labels, tout);
}

// Round 7
// 785.084 us; speedup vs baseline: 1.5875x; 1.1357x over previous
//
#include <hip/hip_runtime.h>
#include <stdint.h>

// RPN GT matcher — exact JAX-semantics reimplementation.
// RNG (verified R3): partitionable counter-mode, counter=(0, flat_idx),
// 32-bit draw = o0 ^ o1; split(key,n)[i] = both words of tf(key,(0,i)).
#define NANCH   262144      // anchors (== 2^18, required by key packing)
#define NB      4           // batch
#define NG      64          // gt boxes per image
#define TGT_FG  153         // int(0.3*512)
#define SB      512         // sample batch
#define IDXMASK 262143u     // 2^18-1, anchor-index field in sort keys
#define NSH     8           // shards per batch (atomic-contention spreading)
#define SHCAP   (NANCH/NSH) // 32768 = 128 blocks * 256 anchors (exact fit)

// ---- workspace layout (bytes); harness poisons ws with 0xAA each launch ----
#define WS_PCNT     0                         // 64 counters on own 64B lines
#define WS_KTH      4096                      // NB u64
#define WS_TBG      4160                      // NB i32
#define WS_DOSAMP   4224                      // NB i32
#define WS_NUMPOS   4288                      // NB i32
#define WS_G2A      4352                      // NB*NG f32 = 1024
#define WS_SAMPKEY  8192                      // NB*SB u64 -> ends 24576
#define WS_ZERO_WORDS 6144                    // zero [0, 24576) as u32
#define WS_GMAXC    32768                     // NB*256*64 f32 = 256 KB
#define WS_A2G      294912                    // NB*NANCH u8
#define WS_NEG      (WS_A2G + NB*NANCH)       // NB*NANCH u32 (8 shards/batch)
#define WS_POS      (WS_NEG + NB*NANCH*4)     // NB*NANCH u64 (~13.3 MB total)

#define PCNT_AT(pcnt, b, sh, L) ((pcnt)[(((b) * NSH + (sh)) * 2 + (L)) * 16])

struct RngKeys { uint32_t kp[NB][2]; uint32_t kn[NB][2]; };

// ---------------- threefry2x32-20, exactly as jax/_src/prng.py -------------
#define TFR(r) { x0 += x1; x1 = (x1 << (r)) | (x1 >> (32 - (r))); x1 ^= x0; }
__host__ __device__ inline void tf2x32(uint32_t k0, uint32_t k1,
                                       uint32_t x0, uint32_t x1,
                                       uint32_t &o0, uint32_t &o1) {
  uint32_t k2 = k0 ^ k1 ^ 0x1BD11BDAu;
  x0 += k0; x1 += k1;
  TFR(13) TFR(15) TFR(26) TFR(6)   x0 += k1; x1 += k2 + 1u;
  TFR(17) TFR(29) TFR(16) TFR(24)  x0 += k2; x1 += k0 + 2u;
  TFR(13) TFR(15) TFR(26) TFR(6)   x0 += k0; x1 += k1 + 3u;
  TFR(17) TFR(29) TFR(16) TFR(24)  x0 += k1; x1 += k2 + 4u;
  TFR(13) TFR(15) TFR(26) TFR(6)   x0 += k2; x1 += k0 + 5u;
  o0 = x0; o1 = x1;
}

// hash with per-element counter i: counter pair (0, i)
__host__ __device__ inline void tf_ctr(uint32_t k0, uint32_t k1, uint32_t i,
                                       uint32_t &o0, uint32_t &o1) {
  tf2x32(k0, k1, 0u, i, o0, o1);
}

// 32-bit random draw for flat element index: o0 ^ o1 (verified R3)
__device__ __forceinline__ uint32_t draw_bits(uint32_t k0, uint32_t k1,
                                              uint32_t idx) {
  uint32_t o0, o1;
  tf_ctr(k0, k1, idx, o0, o1);
  return o0 ^ o1;
}

// ---- threefry core for the categorical hot loop (rotate = alignbit) -------
#define ROTL1(x, r) __builtin_amdgcn_alignbit((x), (x), 32 - (r))
#define TFQ(r) { x0 += x1; x1 = ROTL1(x1, r); x1 ^= x0; }
// caller pre-applies +k0 to x0 and +k1 to x1 (x0 ctr word is 0 -> x0 = k0)
__device__ __forceinline__ uint32_t tf_bits_fast(uint32_t k0, uint32_t k1,
                                                 uint32_t k2, uint32_t x0,
                                                 uint32_t x1) {
  TFQ(13) TFQ(15) TFQ(26) TFQ(6)   x0 += k1; x1 += k2 + 1u;
  TFQ(17) TFQ(29) TFQ(16) TFQ(24)  x0 += k2; x1 += k0 + 2u;
  TFQ(13) TFQ(15) TFQ(26) TFQ(6)   x0 += k0; x1 += k1 + 3u;
  TFQ(17) TFQ(29) TFQ(16) TFQ(24)  x0 += k1; x1 += k2 + 4u;
  TFQ(13) TFQ(15) TFQ(26) TFQ(6)   x0 += k2; x1 += k0 + 5u;
  return x0 ^ x1;
}

// ------------- IoU, bit-identical across passes (no FP contraction) --------
__device__ __forceinline__ float box_area(float x1, float y1, float x2, float y2) {
#pragma clang fp contract(off)
  return ((x2 - x1) + 1.0f) * ((y2 - y1) + 1.0f);
}

__device__ __forceinline__ float iou_pair(float ax1, float ay1, float ax2, float ay2,
                                          float areaA, float gx1, float gy1,
                                          float gx2, float gy2, float areaB) {
#pragma clang fp contract(off)
  float ltx = fmaxf(ax1, gx1), lty = fmaxf(ay1, gy1);
  float rbx = fminf(ax2, gx2), rby = fminf(ay2, gy2);
  float w = fmaxf((rbx - ltx) + 1.0f, 0.0f);
  float h = fmaxf((rby - lty) + 1.0f, 0.0f);
  float inter = w * h;
  return inter / ((areaA + areaB) - inter);
}

// ---------------------------------------------------------------------------
__global__ __launch_bounds__(256) void k_init(unsigned int* w) {
  int i = blockIdx.x * 256 + threadIdx.x;
  if (i < WS_ZERO_WORDS) w[i] = 0u;
}

// Pass A stage 1: per-chunk maxima, NO atomics (R6's 65k-atomic storm on 16
// lines was the hidden ~100+us). gmaxc[b][chunk][j], coalesced 64-f32 store.
__global__ __launch_bounds__(256) void k_g2amax(
    const float4* __restrict__ boxes, const float4* __restrict__ gtb,
    const int* __restrict__ gti, const float* __restrict__ iminfo,
    float* __restrict__ gmaxc) {
  int bx = blockIdx.x;
  int b = bx >> 8, chunk = bx & 255;          // NANCH/1024 = 256 chunks/batch
  int t = threadIdx.x, j = t & 63, sub = t >> 6;
  float4 g = gtb[b * NG + j];
  bool valid = (gti[b * NG + j] == 0);
  float areaB = box_area(g.x, g.y, g.z, g.w);
  float thrx = iminfo[b * 3 + 1] + 1.0f;      // im_w + STRADDLE + 1
  float thry = iminfo[b * 3 + 0] + 1.0f;      // im_h + STRADDLE + 1
  float m = 0.0f;
  int base = chunk * 1024 + sub * 256;
  #pragma unroll 2
  for (int i = 0; i < 256; ++i) {
    float4 bb = boxes[base + i];              // same addr across wave: broadcast
    bool inside = (bb.x >= -0.0f) && (bb.y >= -0.0f) && (bb.z < thrx) && (bb.w < thry);
    float areaA = box_area(bb.x, bb.y, bb.z, bb.w);
    float v = iou_pair(bb.x, bb.y, bb.z, bb.w, areaA, g.x, g.y, g.z, g.w, areaB);
    v = (inside && valid) ? v : 0.0f;
    m = fmaxf(m, v);
  }
  __shared__ float red[4][64];
  red[sub][j] = m;
  __syncthreads();
  if (t < 64) {
    float mm = fmaxf(fmaxf(red[0][t], red[1][t]), fmaxf(red[2][t], red[3][t]));
    gmaxc[((b << 8) + chunk) * 64 + t] = mm;
  }
}

// Pass A stage 2: fold 256 chunk-maxima -> g2a[b][j]. 4 blocks, exact.
__global__ __launch_bounds__(256) void k_g2afin(
    const float* __restrict__ gmaxc, float* __restrict__ g2a) {
  int b = blockIdx.x, t = threadIdx.x;
  int j = t & 63, part = t >> 6;
  float m = 0.0f;
  for (int c = part * 64; c < part * 64 + 64; ++c)
    m = fmaxf(m, gmaxc[((b << 8) + c) * 64 + j]);
  __shared__ float red[4][64];
  red[part][j] = m;
  __syncthreads();
  if (t < 64)
    g2a[b * NG + t] = fmaxf(fmaxf(red[0][t], red[1][t]),
                            fmaxf(red[2][t], red[3][t]));
}

// Pass B: labels init, argmax gt, with_max, pos/neg compaction (sharded,
// block-aggregated atomics: 1 atomic per block per list, padded counters).
__global__ __launch_bounds__(256) void k_label(
    const float4* __restrict__ boxes, const float4* __restrict__ gtb,
    const int* __restrict__ gti, const float* __restrict__ iminfo,
    const float* __restrict__ g2a, float* __restrict__ labels,
    unsigned char* __restrict__ a2g, unsigned long long* __restrict__ pos_keys,
    unsigned int* __restrict__ neg_list, int* __restrict__ pcnt, RngKeys rk) {
  int bx = blockIdx.x;
  int b = bx >> 10, blk = bx & 1023;          // NANCH/256 = 1024 blocks/batch
  int t = threadIdx.x;
  int sh = blk & (NSH - 1);                   // 128 blocks/shard * 256 = SHCAP
  __shared__ float4 sg[NG];
  __shared__ float sab[NG], sval[NG], sadj[NG];
  if (t < NG) {
    float4 g = gtb[b * NG + t];
    sg[t] = g;
    sab[t] = box_area(g.x, g.y, g.z, g.w);
    sval[t] = (gti[b * NG + t] == 0) ? 1.0f : 0.0f;
    float gm = g2a[b * NG + t];
    sadj[t] = (gm == 0.0f) ? 1.0f : gm;       // avoid matching all-zero cols
  }
  __syncthreads();
  int a = blk * 256 + t;
  float4 bb = boxes[a];
  float thrx = iminfo[b * 3 + 1] + 1.0f, thry = iminfo[b * 3 + 0] + 1.0f;
  bool inside = (bb.x >= -0.0f) && (bb.y >= -0.0f) && (bb.z < thrx) && (bb.w < thry);
  float areaA = box_area(bb.x, bb.y, bb.z, bb.w);
  float maxv = 0.0f; int amax = 0; bool wm = false;
  #pragma unroll 8
  for (int j = 0; j < NG; ++j) {
    float4 g = sg[j];
    float v = iou_pair(bb.x, bb.y, bb.z, bb.w, areaA, g.x, g.y, g.z, g.w, sab[j]);
    v = (inside && (sval[j] != 0.0f)) ? v : 0.0f;
    wm = wm || (v == sadj[j]);                 // ensure_closest_box
    if (v > maxv) { maxv = v; amax = j; }      // first-max (== jnp.argmax)
  }
  bool pos = inside && (wm || (maxv >= 0.5f));
  bool neg = inside && (maxv < 0.3f);
  labels[b * NANCH + a] = pos ? 1.0f : -1.0f;
  a2g[b * NANCH + a] = (unsigned char)amax;
  // block-aggregated two-list compaction
  unsigned long long mpos = __ballot(pos);
  unsigned long long mneg = __ballot(neg);
  int lane = t & 63, wid = t >> 6;
  __shared__ int wc[4][2];
  __shared__ int bbase[2];
  if (lane == 0) { wc[wid][0] = __popcll(mpos); wc[wid][1] = __popcll(mneg); }
  __syncthreads();
  if (t == 0) {
    bbase[0] = atomicAdd(&PCNT_AT(pcnt, b, sh, 0),
                         wc[0][0] + wc[1][0] + wc[2][0] + wc[3][0]);
    bbase[1] = atomicAdd(&PCNT_AT(pcnt, b, sh, 1),
                         wc[0][1] + wc[1][1] + wc[2][1] + wc[3][1]);
  }
  __syncthreads();
  unsigned long long lt = (1ull << lane) - 1ull;
  if (pos) {
    int off = bbase[0] + __popcll(mpos & lt);
    for (int w = 0; w < wid; ++w) off += wc[w][0];
    // prio = uniform(kp,(n,)) -> monotone in bits>>9; key: prio desc, idx asc
    uint32_t bits = draw_bits(rk.kp[b][0], rk.kp[b][1], (uint32_t)a);
    unsigned long long key =
        (((unsigned long long)(bits >> 9)) << 18) | (unsigned long long)(IDXMASK - (uint32_t)a);
    pos_keys[(size_t)b * NANCH + (size_t)sh * SHCAP + off] = key;
  }
  if (neg) {
    int off = bbase[1] + __popcll(mneg & lt);
    for (int w = 0; w < wid; ++w) off += wc[w][1];
    neg_list[(size_t)b * NANCH + (size_t)sh * SHCAP + off] = (unsigned int)a;
  }
}

// kth[b] = 153rd-largest pos key. v2: histogram select (2 data passes)
// replacing the 41-round global radix. All keys are DISTINCT (unique anchor
// index in low 18 bits), so kth is unique and exact.
#define HB   4096       // top-12-bit buckets (key is 41 bits: bucket=key>>29)
#define BCAP 3072       // collected-bucket capacity (expected ~np/4096 << cap)
__global__ __launch_bounds__(256) void k_select(
    const unsigned long long* __restrict__ pos_keys, const int* __restrict__ pcnt,
    unsigned long long* __restrict__ kth, int* __restrict__ tbg,
    int* __restrict__ dosamp, int* __restrict__ numpos) {
  int b = blockIdx.x, t = threadIdx.x;
  int lane = t & 63, wid = t >> 6;
  int scnt[NSH]; int np = 0, nn = 0;
  #pragma unroll
  for (int sh = 0; sh < NSH; ++sh) {
    scnt[sh] = PCNT_AT(pcnt, b, sh, 0);
    np += scnt[sh];
    nn += PCNT_AT(pcnt, b, sh, 1);
  }
  int nf = np < TGT_FG ? np : TGT_FG;
  int targ = SB - nf;
  if (t == 0) { tbg[b] = targ; dosamp[b] = (nn > targ) ? 1 : 0; numpos[b] = np; }
  if (np <= TGT_FG) { if (t == 0) kth[b] = 0ull; return; }

  __shared__ unsigned int hist[HB];
  __shared__ unsigned int part[256];
  __shared__ unsigned long long buf[BCAP];
  __shared__ int bufcnt, bucketB, rprime, cw[4];
  for (int i = t; i < HB; i += 256) hist[i] = 0u;
  if (t == 0) { bufcnt = 0; bucketB = -1; }
  __syncthreads();
  // pass 1: bucket histogram
  for (int sh = 0; sh < NSH; ++sh) {
    const unsigned long long* keys = pos_keys + (size_t)b * NANCH + (size_t)sh * SHCAP;
    for (int i = t; i < scnt[sh]; i += 256)
      atomicAdd(&hist[(unsigned int)(keys[i] >> 29)], 1u);
  }
  __syncthreads();
  // suffix scan from the top bucket; thread t owns [t*16, t*16+16)
  unsigned int S = 0;
  #pragma unroll
  for (int k = 0; k < 16; ++k) S += hist[t * 16 + k];
  part[t] = S;
  __syncthreads();
  if (t == 0) {  // part[i] := count of keys in buckets owned by threads > i
    unsigned int run = 0;
    for (int i = 255; i >= 0; --i) { unsigned int p = part[i]; part[i] = run; run += p; }
  }
  __syncthreads();
  {
    unsigned int above = part[t];
    for (int k = 15; k >= 0; --k) {
      unsigned int h = hist[t * 16 + k];
      if (above < TGT_FG && above + h >= TGT_FG) {
        bucketB = t * 16 + k; rprime = TGT_FG - (int)above;  // unique winner
      }
      above += h;
    }
  }
  __syncthreads();
  int B = bucketB, rp = rprime;
  // pass 2: collect bucket-B keys into LDS
  for (int sh = 0; sh < NSH; ++sh) {
    const unsigned long long* keys = pos_keys + (size_t)b * NANCH + (size_t)sh * SHCAP;
    for (int i = t; i < scnt[sh]; i += 256) {
      unsigned long long key = keys[i];
      if ((int)(key >> 29) == B) {
        int p = atomicAdd(&bufcnt, 1);
        if (p < BCAP) buf[p] = key;
      }
    }
  }
  __syncthreads();
  int cnt = bufcnt;
  unsigned int pref = 0u; int r = rp;
  if (cnt <= BCAP) {
    // in-LDS 29-bit radix for the rp-th largest low-29 among bucket-B keys
    for (int bit = 28; bit >= 0; --bit) {
      unsigned int cand = pref | (1u << bit);
      unsigned int mask = (~((1u << bit) - 1u)) & 0x1FFFFFFFu;
      int c = 0;
      for (int i = t; i < cnt; i += 256) {
        unsigned int low = (unsigned int)(buf[i] & 0x1FFFFFFFull);
        c += ((low & mask) == cand) ? 1 : 0;
      }
      #pragma unroll
      for (int off = 32; off; off >>= 1) c += __shfl_xor(c, off, 64);
      if (lane == 0) cw[wid] = c;
      __syncthreads();
      int total = cw[0] + cw[1] + cw[2] + cw[3];
      if (total >= r) pref = cand; else r -= total;
      __syncthreads();
    }
  } else {
    // pathological fallback: global 29-bit radix restricted to bucket B
    for (int bit = 28; bit >= 0; --bit) {
      unsigned int cand = pref | (1u << bit);
      unsigned int mask = (~((1u << bit) - 1u)) & 0x1FFFFFFFu;
      int c = 0;
      for (int sh = 0; sh < NSH; ++sh) {
        const unsigned long long* keys = pos_keys + (size_t)b * NANCH + (size_t)sh * SHCAP;
        for (int i = t; i < scnt[sh]; i += 256) {
          unsigned long long key = keys[i];
          if ((int)(key >> 29) == B) {
            unsigned int low = (unsigned int)(key & 0x1FFFFFFFull);
            c += ((low & mask) == cand) ? 1 : 0;
          }
        }
      }
      #pragma unroll
      for (int off = 32; off; off >>= 1) c += __shfl_xor(c, off, 64);
      if (lane == 0) cw[wid] = c;
      __syncthreads();
      int total = cw[0] + cw[1] + cw[2] + cw[3];
      if (total >= r) pref = cand; else r -= total;
      __syncthreads();
    }
  }
  if (t == 0) kth[b] = (((unsigned long long)B) << 29) | (unsigned long long)pref;
}

// Disable positives below the top-153 priority threshold.
__global__ __launch_bounds__(256) void k_disable(
    const unsigned long long* __restrict__ pos_keys, const int* __restrict__ pcnt,
    const int* __restrict__ numpos, const unsigned long long* __restrict__ kth,
    float* __restrict__ labels) {
  int b = blockIdx.x >> 6, blk = blockIdx.x & 63;
  if (numpos[b] <= TGT_FG) return;
  int sh = blk & (NSH - 1), sub = blk >> 3;
  int cnt = PCNT_AT(pcnt, b, sh, 0);
  unsigned long long K = kth[b];
  const unsigned long long* keys = pos_keys + (size_t)b * NANCH + (size_t)sh * SHCAP;
  for (int i = sub * 256 + threadIdx.x; i < cnt; i += 8 * 256) {
    unsigned long long key = keys[i];
    if (key < K) {
      int a = (int)(IDXMASK - (uint32_t)(key & (unsigned long long)IDXMASK));
      labels[b * NANCH + a] = -1.0f;
    }
  }
}

// categorical(kn, neg?0:-1e9, shape=(512,)) == per-draw key-argmax over negs.
// gumbel strictly monotone in bits>>9; exact-bit ties -> smallest flat index.
// Structure proven in R6: 93.7% VALUBusy, ~608us (near practical VALU issue
// ceiling for 331M threefry hashes). Unchanged this round (control).
__global__ __launch_bounds__(256) void k_cat(
    const unsigned int* __restrict__ neg_list, const int* __restrict__ pcnt,
    const int* __restrict__ tbg, unsigned long long* __restrict__ samp_key,
    RngKeys rk) {
  int bx = blockIdx.x;
  int sh = bx & (NSH - 1);               // shard = chunk of the negative list
  int pr = (bx >> 3) & 255;              // draw pair (s0 = 2*pr)
  int b  = bx >> 11;                     // batch
  int targ = tbg[b];
  int s0 = pr * 2;
  if (s0 >= targ) return;                // dead draws: reference discards them
  int nn = PCNT_AT(pcnt, b, sh, 1);
  uint32_t k0 = rk.kn[b][0], k1 = rk.kn[b][1];
  uint32_t k2 = k0 ^ k1 ^ 0x1BD11BDAu;
  uint32_t xb0 = ((uint32_t)s0 << 18) + k1;
  uint32_t xb1 = ((uint32_t)(s0 + 1) << 18) + k1;
  unsigned long long b0 = 0ull, b1 = 0ull;
  const unsigned int* nl = neg_list + (size_t)b * NANCH + (size_t)sh * SHCAP;
  int i = threadIdx.x;
  if (i < nn) {
    uint32_t a = nl[i];
    for (;;) {
      int inext = i + 256;
      bool has = inext < nn;
      uint32_t an = has ? nl[inext] : 0u;    // 1-deep pipelined load
      unsigned long long inv64 = (unsigned long long)(IDXMASK - a);
      { uint32_t bits = tf_bits_fast(k0, k1, k2, k0, xb0 + a);
        unsigned long long key = (((unsigned long long)(bits >> 9)) << 18) | inv64;
        if (key > b0) b0 = key; }
      { uint32_t bits = tf_bits_fast(k0, k1, k2, k0, xb1 + a);
        unsigned long long key = (((unsigned long long)(bits >> 9)) << 18) | inv64;
        if (key > b1) b1 = key; }
      if (!has) break;
      a = an; i = inext;
    }
  }
  // wave butterfly, then cross-wave merge
  #pragma unroll
  for (int off = 32; off; off >>= 1) {
    unsigned long long o0 = __shfl_xor(b0, off, 64); if (o0 > b0) b0 = o0;
    unsigned long long o1 = __shfl_xor(b1, off, 64); if (o1 > b1) b1 = o1;
  }
  __shared__ unsigned long long red[4][2];
  int lane = threadIdx.x & 63, wid = threadIdx.x >> 6;
  if (lane == 0) { red[wid][0] = b0; red[wid][1] = b1; }
  __syncthreads();
  if (threadIdx.x < 2) {
    int j = threadIdx.x;
    unsigned long long m = red[0][j];
    if (red[1][j] > m) m = red[1][j];
    if (red[2][j] > m) m = red[2][j];
    if (red[3][j] > m) m = red[3][j];
    if (s0 + j < targ) atomicMax(&samp_key[b * SB + s0 + j], m);
  }
}

// Set sampled negatives to 0 (after fg-disable, matching reference order).
__global__ __launch_bounds__(256) void k_scatter(
    const unsigned long long* __restrict__ samp_key, const int* __restrict__ tbg,
    const int* __restrict__ dosamp, float* __restrict__ labels) {
  int b = blockIdx.x >> 1;
  int s = ((blockIdx.x & 1) << 8) | threadIdx.x;
  if (!dosamp[b]) return;
  if (s < tbg[b]) {
    unsigned long long key = samp_key[b * SB + s];
    int a = (int)(IDXMASK - (uint32_t)(key & (unsigned long long)IDXMASK));
    labels[b * NANCH + a] = 0.0f;
  }
}

// bbox_transform_inv for final positives; zeros elsewhere.
__global__ __launch_bounds__(256) void k_targets(
    const float4* __restrict__ boxes, const float4* __restrict__ gtb,
    const unsigned char* __restrict__ a2g, const float* __restrict__ labels,
    float4* __restrict__ tout) {
  int bx = blockIdx.x;
  int b = bx >> 10, blk = bx & 1023;
  int a = blk * 256 + threadIdx.x;
  float lab = labels[b * NANCH + a];
  float4 o = make_float4(0.f, 0.f, 0.f, 0.f);
  if (lab > 0.0f) {
    float4 e = boxes[a];
    float4 g = gtb[b * NG + a2g[b * NANCH + a]];
    float ew = e.z - e.x + 1.0f, eh = e.w - e.y + 1.0f;
    float ecx = e.x + 0.5f * ew, ecy = e.y + 0.5f * eh;
    float gw = g.z - g.x + 1.0f, gh = g.w - g.y + 1.0f;
    float gcx = g.x + 0.5f * gw, gcy = g.y + 0.5f * gh;
    o.x = (gcx - ecx) / ew;
    o.y = (gcy - ecy) / eh;
    o.z = logf(gw / ew);
    o.w = logf(gh / eh);
  }
  tout[(size_t)b * NANCH + a] = o;
}

// ---------------------------------------------------------------------------
extern "C" void kernel_launch(void* const* d_in, const int* in_sizes, int n_in,
                              void* d_out, int out_size, void* d_ws, size_t ws_size,
                              hipStream_t stream) {
  const float4* boxes  = (const float4*)d_in[0];
  const float4* gtb    = (const float4*)d_in[1];
  // d_in[2] = gt_labels: unused, exactly like the reference
  const int*    gti    = (const int*)d_in[3];
  const float*  iminfo = (const float*)d_in[4];
  float*  labels = (float*)d_out;                       // [B][N] as f32
  float4* tout   = (float4*)(labels + (size_t)NB * NANCH); // [B][N][4]

  char* wsb = (char*)d_ws;  // needs ~13.3 MB
  int*                pcnt     = (int*)(wsb + WS_PCNT);
  unsigned long long* kth      = (unsigned long long*)(wsb + WS_KTH);
  int*                tbg      = (int*)(wsb + WS_TBG);
  int*                dosamp   = (int*)(wsb + WS_DOSAMP);
  int*                numpos   = (int*)(wsb + WS_NUMPOS);
  float*              g2a_f    = (float*)(wsb + WS_G2A);
  unsigned long long* samp_key = (unsigned long long*)(wsb + WS_SAMPKEY);
  float*              gmaxc    = (float*)(wsb + WS_GMAXC);
  unsigned char*      a2g      = (unsigned char*)(wsb + WS_A2G);
  unsigned int*       neg_list = (unsigned int*)(wsb + WS_NEG);
  unsigned long long* pos_keys = (unsigned long long*)(wsb + WS_POS);

  // Host-side key derivation: root=(0,42); split(root,4) -> per-image key;
  // split(key_b,2) -> (kp, kn). Split keys are the FULL 64-bit outputs.
  RngKeys rk;
  for (int b = 0; b < NB; ++b) {
    uint32_t a0, a1;
    tf_ctr(0u, 42u, (uint32_t)b, a0, a1);                // keys[b]
    tf_ctr(a0, a1, 0u, rk.kp[b][0], rk.kp[b][1]);        // subkey 0 = kp
    tf_ctr(a0, a1, 1u, rk.kn[b][0], rk.kn[b][1]);        // subkey 1 = kn
  }

  k_init   <<<24, 256, 0, stream>>>((unsigned int*)wsb);
  k_g2amax <<<NB * (NANCH / 1024), 256, 0, stream>>>(boxes, gtb, gti, iminfo, gmaxc);
  k_g2afin <<<NB, 256, 0, stream>>>(gmaxc, g2a_f);
  k_label  <<<NB * (NANCH / 256), 256, 0, stream>>>(boxes, gtb, gti, iminfo, g2a_f,
                                                    labels, a2g, pos_keys, neg_list,
                                                    pcnt, rk);
  k_select <<<NB, 256, 0, stream>>>(pos_keys, pcnt, kth, tbg, dosamp, numpos);
  k_disable<<<NB * 64, 256, 0, stream>>>(pos_keys, pcnt, numpos, kth, labels);
  k_cat    <<<NB * 256 * NSH, 256, 0, stream>>>(neg_list, pcnt, tbg, samp_key, rk);
  k_scatter<<<NB * 2, 256, 0, stream>>>(samp_key, tbg, dosamp, labels);
  k_targets<<<NB * (NANCH / 256), 256, 0, stream>>>(boxes, gtb, a2g, labels, tout);
}

// Round 8
// 745.732 us; speedup vs baseline: 1.6712x; 1.0528x over previous
//
#include <hip/hip_runtime.h>
#include <stdint.h>

// RPN GT matcher — exact JAX-semantics reimplementation.
// RNG (verified R3): partitionable counter-mode, counter=(0, flat_idx),
// 32-bit draw = o0 ^ o1; split(key,n)[i] = both words of tf(key,(0,i)).
#define NANCH   262144      // anchors (== 2^18, required by key packing)
#define NB      4           // batch
#define NG      64          // gt boxes per image
#define TGT_FG  153         // int(0.3*512)
#define SB      512         // sample batch
#define IDXMASK 262143u     // 2^18-1, anchor-index field in sort keys
#define NSH     8           // shards per batch (atomic-contention spreading)
#define SHCAP   (NANCH/NSH) // 32768 = 128 blocks * 256 anchors (exact fit)

// ---- workspace layout (bytes); harness poisons ws with 0xAA each launch ----
#define WS_PCNT     0                         // 64 counters on own 64B lines
#define WS_KTH      4096                      // NB u64
#define WS_TBG      4160                      // NB i32
#define WS_DOSAMP   4224                      // NB i32
#define WS_NUMPOS   4288                      // NB i32
#define WS_G2A      4352                      // NB*NG f32 = 1024
#define WS_SAMPKEY  8192                      // NB*SB u64 -> ends 24576
#define WS_ZERO_BYTES 24576                   // hipMemsetAsync range
#define WS_GMAXC    32768                     // NB*256*64 f32 = 256 KB
#define WS_A2G      294912                    // NB*NANCH u8
#define WS_NEG      (WS_A2G + NB*NANCH)       // NB*NANCH u32 (8 shards/batch)
#define WS_POS      (WS_NEG + NB*NANCH*4)     // NB*NANCH u64 (~13.3 MB total)

#define PCNT_AT(pcnt, b, sh, L) ((pcnt)[(((b) * NSH + (sh)) * 2 + (L)) * 16])

struct RngKeys { uint32_t kp[NB][2]; uint32_t kn[NB][2]; };

// ---------------- threefry2x32-20, exactly as jax/_src/prng.py -------------
#define TFR(r) { x0 += x1; x1 = (x1 << (r)) | (x1 >> (32 - (r))); x1 ^= x0; }
__host__ __device__ inline void tf2x32(uint32_t k0, uint32_t k1,
                                       uint32_t x0, uint32_t x1,
                                       uint32_t &o0, uint32_t &o1) {
  uint32_t k2 = k0 ^ k1 ^ 0x1BD11BDAu;
  x0 += k0; x1 += k1;
  TFR(13) TFR(15) TFR(26) TFR(6)   x0 += k1; x1 += k2 + 1u;
  TFR(17) TFR(29) TFR(16) TFR(24)  x0 += k2; x1 += k0 + 2u;
  TFR(13) TFR(15) TFR(26) TFR(6)   x0 += k0; x1 += k1 + 3u;
  TFR(17) TFR(29) TFR(16) TFR(24)  x0 += k1; x1 += k2 + 4u;
  TFR(13) TFR(15) TFR(26) TFR(6)   x0 += k2; x1 += k0 + 5u;
  o0 = x0; o1 = x1;
}

// hash with per-element counter i: counter pair (0, i)
__host__ __device__ inline void tf_ctr(uint32_t k0, uint32_t k1, uint32_t i,
                                       uint32_t &o0, uint32_t &o1) {
  tf2x32(k0, k1, 0u, i, o0, o1);
}

// 32-bit random draw for flat element index: o0 ^ o1 (verified R3)
__device__ __forceinline__ uint32_t draw_bits(uint32_t k0, uint32_t k1,
                                              uint32_t idx) {
  uint32_t o0, o1;
  tf_ctr(k0, k1, idx, o0, o1);
  return o0 ^ o1;
}

// ---- threefry core for the categorical hot loop (rotate = alignbit) -------
#define ROTL1(x, r) __builtin_amdgcn_alignbit((x), (x), 32 - (r))
#define TFQ(r) { x0 += x1; x1 = ROTL1(x1, r); x1 ^= x0; }
// caller pre-applies +k0 to x0 and +k1 to x1 (x0 ctr word is 0 -> x0 = k0)
__device__ __forceinline__ uint32_t tf_bits_fast(uint32_t k0, uint32_t k1,
                                                 uint32_t k2, uint32_t x0,
                                                 uint32_t x1) {
  TFQ(13) TFQ(15) TFQ(26) TFQ(6)   x0 += k1; x1 += k2 + 1u;
  TFQ(17) TFQ(29) TFQ(16) TFQ(24)  x0 += k2; x1 += k0 + 2u;
  TFQ(13) TFQ(15) TFQ(26) TFQ(6)   x0 += k0; x1 += k1 + 3u;
  TFQ(17) TFQ(29) TFQ(16) TFQ(24)  x0 += k1; x1 += k2 + 4u;
  TFQ(13) TFQ(15) TFQ(26) TFQ(6)   x0 += k2; x1 += k0 + 5u;
  return x0 ^ x1;
}

// ------------- IoU, bit-identical across passes (no FP contraction) --------
__device__ __forceinline__ float box_area(float x1, float y1, float x2, float y2) {
#pragma clang fp contract(off)
  return ((x2 - x1) + 1.0f) * ((y2 - y1) + 1.0f);
}

__device__ __forceinline__ float iou_pair(float ax1, float ay1, float ax2, float ay2,
                                          float areaA, float gx1, float gy1,
                                          float gx2, float gy2, float areaB) {
#pragma clang fp contract(off)
  float ltx = fmaxf(ax1, gx1), lty = fmaxf(ay1, gy1);
  float rbx = fminf(ax2, gx2), rby = fminf(ay2, gy2);
  float w = fmaxf((rbx - ltx) + 1.0f, 0.0f);
  float h = fmaxf((rby - lty) + 1.0f, 0.0f);
  float inter = w * h;
  return inter / ((areaA + areaB) - inter);
}

// ---------------------------------------------------------------------------
// Pass A stage 1: per-chunk maxima, no atomics. gmaxc[b][chunk][j].
__global__ __launch_bounds__(256) void k_g2amax(
    const float4* __restrict__ boxes, const float4* __restrict__ gtb,
    const int* __restrict__ gti, const float* __restrict__ iminfo,
    float* __restrict__ gmaxc) {
  int bx = blockIdx.x;
  int b = bx >> 8, chunk = bx & 255;          // NANCH/1024 = 256 chunks/batch
  int t = threadIdx.x, j = t & 63, sub = t >> 6;
  float4 g = gtb[b * NG + j];
  bool valid = (gti[b * NG + j] == 0);
  float areaB = box_area(g.x, g.y, g.z, g.w);
  float thrx = iminfo[b * 3 + 1] + 1.0f;      // im_w + STRADDLE + 1
  float thry = iminfo[b * 3 + 0] + 1.0f;      // im_h + STRADDLE + 1
  float m = 0.0f;
  int base = chunk * 1024 + sub * 256;
  #pragma unroll 2
  for (int i = 0; i < 256; ++i) {
    float4 bb = boxes[base + i];              // same addr across wave: broadcast
    bool inside = (bb.x >= -0.0f) && (bb.y >= -0.0f) && (bb.z < thrx) && (bb.w < thry);
    float areaA = box_area(bb.x, bb.y, bb.z, bb.w);
    float v = iou_pair(bb.x, bb.y, bb.z, bb.w, areaA, g.x, g.y, g.z, g.w, areaB);
    v = (inside && valid) ? v : 0.0f;
    m = fmaxf(m, v);
  }
  __shared__ float red[4][64];
  red[sub][j] = m;
  __syncthreads();
  if (t < 64) {
    float mm = fmaxf(fmaxf(red[0][t], red[1][t]), fmaxf(red[2][t], red[3][t]));
    gmaxc[((b << 8) + chunk) * 64 + t] = mm;
  }
}

// Pass A stage 2: fold 256 chunk-maxima -> g2a[b][j]. 4 blocks, exact.
__global__ __launch_bounds__(256) void k_g2afin(
    const float* __restrict__ gmaxc, float* __restrict__ g2a) {
  int b = blockIdx.x, t = threadIdx.x;
  int j = t & 63, part = t >> 6;
  float m = 0.0f;
  for (int c = part * 64; c < part * 64 + 64; ++c)
    m = fmaxf(m, gmaxc[((b << 8) + c) * 64 + j]);
  __shared__ float red[4][64];
  red[part][j] = m;
  __syncthreads();
  if (t < 64)
    g2a[b * NG + t] = fmaxf(fmaxf(red[0][t], red[1][t]),
                            fmaxf(red[2][t], red[3][t]));
}

// Pass B: labels init, argmax gt, with_max, pos/neg compaction (sharded,
// block-aggregated atomics: 1 atomic per block per list, padded counters).
__global__ __launch_bounds__(256) void k_label(
    const float4* __restrict__ boxes, const float4* __restrict__ gtb,
    const int* __restrict__ gti, const float* __restrict__ iminfo,
    const float* __restrict__ g2a, float* __restrict__ labels,
    unsigned char* __restrict__ a2g, unsigned long long* __restrict__ pos_keys,
    unsigned int* __restrict__ neg_list, int* __restrict__ pcnt, RngKeys rk) {
  int bx = blockIdx.x;
  int b = bx >> 10, blk = bx & 1023;          // NANCH/256 = 1024 blocks/batch
  int t = threadIdx.x;
  int sh = blk & (NSH - 1);                   // 128 blocks/shard * 256 = SHCAP
  __shared__ float4 sg[NG];
  __shared__ float sab[NG], sval[NG], sadj[NG];
  if (t < NG) {
    float4 g = gtb[b * NG + t];
    sg[t] = g;
    sab[t] = box_area(g.x, g.y, g.z, g.w);
    sval[t] = (gti[b * NG + t] == 0) ? 1.0f : 0.0f;
    float gm = g2a[b * NG + t];
    sadj[t] = (gm == 0.0f) ? 1.0f : gm;       // avoid matching all-zero cols
  }
  __syncthreads();
  int a = blk * 256 + t;
  float4 bb = boxes[a];
  float thrx = iminfo[b * 3 + 1] + 1.0f, thry = iminfo[b * 3 + 0] + 1.0f;
  bool inside = (bb.x >= -0.0f) && (bb.y >= -0.0f) && (bb.z < thrx) && (bb.w < thry);
  float areaA = box_area(bb.x, bb.y, bb.z, bb.w);
  float maxv = 0.0f; int amax = 0; bool wm = false;
  #pragma unroll 8
  for (int j = 0; j < NG; ++j) {
    float4 g = sg[j];
    float v = iou_pair(bb.x, bb.y, bb.z, bb.w, areaA, g.x, g.y, g.z, g.w, sab[j]);
    v = (inside && (sval[j] != 0.0f)) ? v : 0.0f;
    wm = wm || (v == sadj[j]);                 // ensure_closest_box
    if (v > maxv) { maxv = v; amax = j; }      // first-max (== jnp.argmax)
  }
  bool pos = inside && (wm || (maxv >= 0.5f));
  bool neg = inside && (maxv < 0.3f);
  labels[b * NANCH + a] = pos ? 1.0f : -1.0f;
  a2g[b * NANCH + a] = (unsigned char)amax;
  // block-aggregated two-list compaction
  unsigned long long mpos = __ballot(pos);
  unsigned long long mneg = __ballot(neg);
  int lane = t & 63, wid = t >> 6;
  __shared__ int wc[4][2];
  __shared__ int bbase[2];
  if (lane == 0) { wc[wid][0] = __popcll(mpos); wc[wid][1] = __popcll(mneg); }
  __syncthreads();
  if (t == 0) {
    bbase[0] = atomicAdd(&PCNT_AT(pcnt, b, sh, 0),
                         wc[0][0] + wc[1][0] + wc[2][0] + wc[3][0]);
    bbase[1] = atomicAdd(&PCNT_AT(pcnt, b, sh, 1),
                         wc[0][1] + wc[1][1] + wc[2][1] + wc[3][1]);
  }
  __syncthreads();
  unsigned long long lt = (1ull << lane) - 1ull;
  if (pos) {
    int off = bbase[0] + __popcll(mpos & lt);
    for (int w = 0; w < wid; ++w) off += wc[w][0];
    // prio = uniform(kp,(n,)) -> monotone in bits>>9; key: prio desc, idx asc
    uint32_t bits = draw_bits(rk.kp[b][0], rk.kp[b][1], (uint32_t)a);
    unsigned long long key =
        (((unsigned long long)(bits >> 9)) << 18) | (unsigned long long)(IDXMASK - (uint32_t)a);
    pos_keys[(size_t)b * NANCH + (size_t)sh * SHCAP + off] = key;
  }
  if (neg) {
    int off = bbase[1] + __popcll(mneg & lt);
    for (int w = 0; w < wid; ++w) off += wc[w][1];
    neg_list[(size_t)b * NANCH + (size_t)sh * SHCAP + off] = (unsigned int)a;
  }
}

// Fused dispatch: blocks 0..3 = select (kth/tbg/dosamp/numpos, 41-round radix
// over ~np keys — runs on 4 CUs, fully hidden under cat's ~600us); blocks
// 4.. = categorical draws. cat computes targ from pcnt directly, so it does
// NOT depend on select's output (consumed only by later dispatches).
__global__ __launch_bounds__(256) void k_catsel(
    const unsigned int* __restrict__ neg_list,
    const unsigned long long* __restrict__ pos_keys,
    const int* __restrict__ pcnt, unsigned long long* __restrict__ samp_key,
    unsigned long long* __restrict__ kth, int* __restrict__ tbg,
    int* __restrict__ dosamp, int* __restrict__ numpos, RngKeys rk) {
  int bx = blockIdx.x;
  int t = threadIdx.x, lane = t & 63, wid = t >> 6;

  if (bx < NB) {                         // ---------------- select path
    int b = bx;
    __shared__ int cw[4];
    int scnt[NSH]; int np = 0, nnb = 0;
    #pragma unroll
    for (int sh = 0; sh < NSH; ++sh) {
      scnt[sh] = PCNT_AT(pcnt, b, sh, 0);
      np += scnt[sh];
      nnb += PCNT_AT(pcnt, b, sh, 1);
    }
    int nf = np < TGT_FG ? np : TGT_FG;
    int targ = SB - nf;
    if (t == 0) { tbg[b] = targ; dosamp[b] = (nnb > targ) ? 1 : 0; numpos[b] = np; }
    if (np <= TGT_FG) { if (t == 0) kth[b] = 0ull; return; }
    unsigned long long pref = 0ull;
    int r = TGT_FG;
    for (int bit = 40; bit >= 0; --bit) {
      unsigned long long cand = pref | (1ull << bit);
      unsigned long long mask = ~((1ull << bit) - 1ull);
      int c = 0;
      for (int sh = 0; sh < NSH; ++sh) {
        const unsigned long long* keys =
            pos_keys + (size_t)b * NANCH + (size_t)sh * SHCAP;
        for (int i = t; i < scnt[sh]; i += 256)
          c += ((keys[i] & mask) == cand) ? 1 : 0;
      }
      #pragma unroll
      for (int off = 32; off; off >>= 1) c += __shfl_xor(c, off, 64);
      __syncthreads();
      if (lane == 0) cw[wid] = c;
      __syncthreads();
      int total = cw[0] + cw[1] + cw[2] + cw[3];
      if (total >= r) pref = cand; else r -= total;
    }
    if (t == 0) kth[b] = pref;
    return;
  }

  // ---------------- cat path: per-draw key-argmax over the negatives.
  // gumbel strictly monotone in bits>>9; exact-bit ties -> smallest flat index.
  int bx2 = bx - NB;
  int sh = bx2 & (NSH - 1);              // shard = chunk of the negative list
  int pr = (bx2 >> 3) & 255;             // draw pair (s0 = 2*pr)
  int b  = bx2 >> 11;                    // batch
  int np = 0;
  #pragma unroll
  for (int s = 0; s < NSH; ++s) np += PCNT_AT(pcnt, b, s, 0);
  int targ = SB - (np < TGT_FG ? np : TGT_FG);
  int s0 = pr * 2;
  if (s0 >= targ) return;                // dead draws: reference discards them
  int nn = PCNT_AT(pcnt, b, sh, 1);
  uint32_t k0 = rk.kn[b][0], k1 = rk.kn[b][1];
  uint32_t k2 = k0 ^ k1 ^ 0x1BD11BDAu;
  uint32_t xb0 = ((uint32_t)s0 << 18) + k1;
  uint32_t xb1 = ((uint32_t)(s0 + 1) << 18) + k1;
  unsigned long long b0 = 0ull, b1 = 0ull;
  const unsigned int* nl = neg_list + (size_t)b * NANCH + (size_t)sh * SHCAP;
#define PROC1(A) { uint32_t a_ = (A); \
    unsigned long long inv64 = (unsigned long long)(IDXMASK - a_); \
    { uint32_t bits = tf_bits_fast(k0, k1, k2, k0, xb0 + a_); \
      unsigned long long key = (((unsigned long long)(bits >> 9)) << 18) | inv64; \
      if (key > b0) b0 = key; } \
    { uint32_t bits = tf_bits_fast(k0, k1, k2, k0, xb1 + a_); \
      unsigned long long key = (((unsigned long long)(bits >> 9)) << 18) | inv64; \
      if (key > b1) b1 = key; } }
  // uint4 main loop (4 elems, 8 hashes per iter), scalar tail
  int nv = nn >> 2;
  const uint4* nl4 = (const uint4*)nl;
  for (int iv = t; iv < nv; iv += 256) {
    uint4 q = nl4[iv];
    PROC1(q.x) PROC1(q.y) PROC1(q.z) PROC1(q.w)
  }
  for (int i = (nv << 2) + t; i < nn; i += 256) { PROC1(nl[i]) }
#undef PROC1
  // wave butterfly, then cross-wave merge
  #pragma unroll
  for (int off = 32; off; off >>= 1) {
    unsigned long long o0 = __shfl_xor(b0, off, 64); if (o0 > b0) b0 = o0;
    unsigned long long o1 = __shfl_xor(b1, off, 64); if (o1 > b1) b1 = o1;
  }
  __shared__ unsigned long long red[4][2];
  if (lane == 0) { red[wid][0] = b0; red[wid][1] = b1; }
  __syncthreads();
  if (t < 2) {
    int j = t;
    unsigned long long m = red[0][j];
    if (red[1][j] > m) m = red[1][j];
    if (red[2][j] > m) m = red[2][j];
    if (red[3][j] > m) m = red[3][j];
    if (s0 + j < targ) atomicMax(&samp_key[b * SB + s0 + j], m);
  }
}

// Disable positives below the top-153 priority threshold.
__global__ __launch_bounds__(256) void k_disable(
    const unsigned long long* __restrict__ pos_keys, const int* __restrict__ pcnt,
    const int* __restrict__ numpos, const unsigned long long* __restrict__ kth,
    float* __restrict__ labels) {
  int b = blockIdx.x >> 6, blk = blockIdx.x & 63;
  if (numpos[b] <= TGT_FG) return;
  int sh = blk & (NSH - 1), sub = blk >> 3;
  int cnt = PCNT_AT(pcnt, b, sh, 0);
  unsigned long long K = kth[b];
  const unsigned long long* keys = pos_keys + (size_t)b * NANCH + (size_t)sh * SHCAP;
  for (int i = sub * 256 + threadIdx.x; i < cnt; i += 8 * 256) {
    unsigned long long key = keys[i];
    if (key < K) {
      int a = (int)(IDXMASK - (uint32_t)(key & (unsigned long long)IDXMASK));
      labels[b * NANCH + a] = -1.0f;
    }
  }
}

// Set sampled negatives to 0 (after fg-disable, matching reference order).
__global__ __launch_bounds__(256) void k_scatter(
    const unsigned long long* __restrict__ samp_key, const int* __restrict__ tbg,
    const int* __restrict__ dosamp, float* __restrict__ labels) {
  int b = blockIdx.x >> 1;
  int s = ((blockIdx.x & 1) << 8) | threadIdx.x;
  if (!dosamp[b]) return;
  if (s < tbg[b]) {
    unsigned long long key = samp_key[b * SB + s];
    int a = (int)(IDXMASK - (uint32_t)(key & (unsigned long long)IDXMASK));
    labels[b * NANCH + a] = 0.0f;
  }
}

// bbox_transform_inv for final positives; zeros elsewhere.
__global__ __launch_bounds__(256) void k_targets(
    const float4* __restrict__ boxes, const float4* __restrict__ gtb,
    const unsigned char* __restrict__ a2g, const float* __restrict__ labels,
    float4* __restrict__ tout) {
  int bx = blockIdx.x;
  int b = bx >> 10, blk = bx & 1023;
  int a = blk * 256 + threadIdx.x;
  float lab = labels[b * NANCH + a];
  float4 o = make_float4(0.f, 0.f, 0.f, 0.f);
  if (lab > 0.0f) {
    float4 e = boxes[a];
    float4 g = gtb[b * NG + a2g[b * NANCH + a]];
    float ew = e.z - e.x + 1.0f, eh = e.w - e.y + 1.0f;
    float ecx = e.x + 0.5f * ew, ecy = e.y + 0.5f * eh;
    float gw = g.z - g.x + 1.0f, gh = g.w - g.y + 1.0f;
    float gcx = g.x + 0.5f * gw, gcy = g.y + 0.5f * gh;
    o.x = (gcx - ecx) / ew;
    o.y = (gcy - ecy) / eh;
    o.z = logf(gw / ew);
    o.w = logf(gh / eh);
  }
  tout[(size_t)b * NANCH + a] = o;
}

// ---------------------------------------------------------------------------
extern "C" void kernel_launch(void* const* d_in, const int* in_sizes, int n_in,
                              void* d_out, int out_size, void* d_ws, size_t ws_size,
                              hipStream_t stream) {
  const float4* boxes  = (const float4*)d_in[0];
  const float4* gtb    = (const float4*)d_in[1];
  // d_in[2] = gt_labels: unused, exactly like the reference
  const int*    gti    = (const int*)d_in[3];
  const float*  iminfo = (const float*)d_in[4];
  float*  labels = (float*)d_out;                       // [B][N] as f32
  float4* tout   = (float4*)(labels + (size_t)NB * NANCH); // [B][N][4]

  char* wsb = (char*)d_ws;  // needs ~13.3 MB
  int*                pcnt     = (int*)(wsb + WS_PCNT);
  unsigned long long* kth      = (unsigned long long*)(wsb + WS_KTH);
  int*                tbg      = (int*)(wsb + WS_TBG);
  int*                dosamp   = (int*)(wsb + WS_DOSAMP);
  int*                numpos   = (int*)(wsb + WS_NUMPOS);
  float*              g2a_f    = (float*)(wsb + WS_G2A);
  unsigned long long* samp_key = (unsigned long long*)(wsb + WS_SAMPKEY);
  float*              gmaxc    = (float*)(wsb + WS_GMAXC);
  unsigned char*      a2g      = (unsigned char*)(wsb + WS_A2G);
  unsigned int*       neg_list = (unsigned int*)(wsb + WS_NEG);
  unsigned long long* pos_keys = (unsigned long long*)(wsb + WS_POS);

  // Host-side key derivation: root=(0,42); split(root,4) -> per-image key;
  // split(key_b,2) -> (kp, kn). Split keys are the FULL 64-bit outputs.
  RngKeys rk;
  for (int b = 0; b < NB; ++b) {
    uint32_t a0, a1;
    tf_ctr(0u, 42u, (uint32_t)b, a0, a1);                // keys[b]
    tf_ctr(a0, a1, 0u, rk.kp[b][0], rk.kp[b][1]);        // subkey 0 = kp
    tf_ctr(a0, a1, 1u, rk.kn[b][0], rk.kn[b][1]);        // subkey 1 = kn
  }

  hipMemsetAsync(wsb, 0, WS_ZERO_BYTES, stream);  // counters/samp_key zeroing
  k_g2amax <<<NB * (NANCH / 1024), 256, 0, stream>>>(boxes, gtb, gti, iminfo, gmaxc);
  k_g2afin <<<NB, 256, 0, stream>>>(gmaxc, g2a_f);
  k_label  <<<NB * (NANCH / 256), 256, 0, stream>>>(boxes, gtb, gti, iminfo, g2a_f,
                                                    labels, a2g, pos_keys, neg_list,
                                                    pcnt, rk);
  k_catsel <<<NB + NB * 256 * NSH, 256, 0, stream>>>(neg_list, pos_keys, pcnt,
                                                     samp_key, kth, tbg, dosamp,
                                                     numpos, rk);
  k_disable<<<NB * 64, 256, 0, stream>>>(pos_keys, pcnt, numpos, kth, labels);
  k_scatter<<<NB * 2, 256, 0, stream>>>(samp_key, tbg, dosamp, labels);
  k_targets<<<NB * (NANCH / 256), 256, 0, stream>>>(boxes, gtb, a2g, labels, tout);
}